// Round 1
// baseline (1989.010 us; speedup 1.0000x reference)
//
#include <hip/hip_runtime.h>
#include <math.h>

// B=16, N=1024, C=768, H=12, HD=64, num_mini_batch=1 (m=1024)
// out = proj( TTT_scan( qkv(x) ) )

#define Bdim 16
#define Ndim 1024
#define Cdim 768
#define Hdim 12
#define HDdim 64

__device__ __forceinline__ float wred(float v) {
    #pragma unroll
    for (int o = 32; o > 0; o >>= 1) v += __shfl_xor(v, o);
    return v;
}

// ---------------- GEMM: C[M,N] = A[M,K] @ B[N,K]^T + bias ----------------
// BIAS_MODE 0: qkv bias = concat(q_bias, zeros, v_bias)   (b0=q_bias, b1=v_bias)
// BIAS_MODE 1: plain bias b0[col]
template<int BIAS_MODE>
__global__ __launch_bounds__(256) void gemm_abt(
    const float* __restrict__ A, const float* __restrict__ B,
    const float* __restrict__ b0, const float* __restrict__ b1v,
    float* __restrict__ C, int M, int N, int K)
{
    __shared__ float As[16][64];
    __shared__ float Bs[16][64];
    const int tid  = threadIdx.x;
    const int row0 = blockIdx.x * 64;
    const int col0 = blockIdx.y * 64;
    const int lr = tid >> 2;          // 0..63 row-in-tile for staging
    const int lq = (tid & 3) << 2;    // 0,4,8,12 k-offset for staging
    const int tm = (tid >> 4) << 2;   // 0..60 step 4 (m sub-tile)
    const int tn = (tid & 15) << 2;   // 0..60 step 4 (n sub-tile)

    const float* Ap = A + (size_t)(row0 + lr) * K + lq;
    const float* Bp = B + (size_t)(col0 + lr) * K + lq;

    float acc[4][4] = {};

    for (int k0 = 0; k0 < K; k0 += 16) {
        float4 av = *(const float4*)(Ap + k0);
        float4 bv = *(const float4*)(Bp + k0);
        __syncthreads();
        As[lq+0][lr] = av.x; As[lq+1][lr] = av.y; As[lq+2][lr] = av.z; As[lq+3][lr] = av.w;
        Bs[lq+0][lr] = bv.x; Bs[lq+1][lr] = bv.y; Bs[lq+2][lr] = bv.z; Bs[lq+3][lr] = bv.w;
        __syncthreads();
        #pragma unroll
        for (int kk = 0; kk < 16; ++kk) {
            float4 a  = *(const float4*)&As[kk][tm];
            float4 bb = *(const float4*)&Bs[kk][tn];
            acc[0][0] += a.x*bb.x; acc[0][1] += a.x*bb.y; acc[0][2] += a.x*bb.z; acc[0][3] += a.x*bb.w;
            acc[1][0] += a.y*bb.x; acc[1][1] += a.y*bb.y; acc[1][2] += a.y*bb.z; acc[1][3] += a.y*bb.w;
            acc[2][0] += a.z*bb.x; acc[2][1] += a.z*bb.y; acc[2][2] += a.z*bb.z; acc[2][3] += a.z*bb.w;
            acc[3][0] += a.w*bb.x; acc[3][1] += a.w*bb.y; acc[3][2] += a.w*bb.z; acc[3][3] += a.w*bb.w;
        }
    }

    const int c = col0 + tn;
    float bias[4];
    #pragma unroll
    for (int j = 0; j < 4; ++j) {
        int cc = c + j;
        if (BIAS_MODE == 0) bias[j] = (cc < 768) ? b0[cc] : (cc < 1536 ? 0.f : b1v[cc - 1536]);
        else                bias[j] = b0[cc];
    }
    #pragma unroll
    for (int i = 0; i < 4; ++i) {
        int r = row0 + tm + i;
        float4 o;
        o.x = acc[i][0] + bias[0];
        o.y = acc[i][1] + bias[1];
        o.z = acc[i][2] + bias[2];
        o.w = acc[i][3] + bias[3];
        *(float4*)&C[(size_t)r * N + c] = o;
    }
}

// ---------------- eta: sigmoid(x . lrw_h + lrb_h)/64, [B,H,N] ----------------
__global__ __launch_bounds__(256) void eta_kernel(
    const float* __restrict__ x, const float* __restrict__ lrw,
    const float* __restrict__ lrb, float* __restrict__ eta)
{
    __shared__ float xs[768];
    const int bn = blockIdx.x;               // b*1024 + n
    const int tid = threadIdx.x, lane = tid & 63, w = tid >> 6;
    const float* xrow = x + (size_t)bn * Cdim;
    if (tid < 192) *(float4*)&xs[tid*4] = *(const float4*)&xrow[tid*4];
    __syncthreads();
    const int b = bn >> 10, n = bn & 1023;
    for (int h = w; h < Hdim; h += 4) {
        float p = 0.f;
        const float* wr = lrw + h * Cdim;
        #pragma unroll
        for (int j = 0; j < 12; ++j) p += xs[lane + j*64] * wr[lane + j*64];
        p = wred(p);
        if (lane == 0) {
            float v = p + lrb[h];
            eta[((size_t)b*Hdim + h)*Ndim + n] = (1.f / (1.f + expf(-v))) * 0.015625f; // sigmoid/64
        }
    }
}

// ---------------- TTT scan (single mini-batch): one block per (b,h) ----------------
__global__ __launch_bounds__(256) void ttt_kernel(
    const float* __restrict__ qkv,    // [B*N, 2304]  (q | k | v), col = which*768 + h*64 + d
    const float* __restrict__ eta,    // [B,H,N]
    const float* __restrict__ W1g,    // [H,64,64]
    const float* __restrict__ b1g,    // [H,64]
    const float* __restrict__ gammag, // [H,64]
    const float* __restrict__ betag,  // [H,64]
    float* __restrict__ inner)        // [B*N, 768], col = h*64 + d
{
    const int bh = blockIdx.x;
    const int b = bh / Hdim, h = bh % Hdim;
    const int tid = threadIdx.x, lane = tid & 63, w = tid >> 6;
    const int e = lane, dbase = w * 16;

    __shared__ float W1s[64][64];
    __shared__ float XSs[64][64];
    __shared__ float Gs[64][64];
    __shared__ float b1s[64], gms[64], bts[64], bn1s[64];
    __shared__ float gb1p[4][64];

    for (int i = tid; i < 4096; i += 256) ((float*)W1s)[i] = W1g[h*4096 + i];
    if (tid < 64) {
        b1s[tid] = b1g[h*64 + tid];
        gms[tid] = gammag[h*64 + tid];
        bts[tid] = betag[h*64 + tid];
    }
    float acc[16];
    #pragma unroll
    for (int i = 0; i < 16; ++i) acc[i] = 0.f;
    float gb1 = 0.f;

    const float* qkv_b = qkv + (size_t)b * Ndim * 2304 + h * 64;
    const float* eta_b = eta + ((size_t)b * Hdim + h) * Ndim;
    __syncthreads();

    // ---- phase 1: Z1 = XK@W1 + b1 ; g = LN-L2-bwd ; accumulate grad_W1, grad_b1 ----
    for (int c0 = 0; c0 < Ndim; c0 += 64) {
        // stage XK chunk [64][64]
        #pragma unroll
        for (int j = 0; j < 4; ++j) {
            int f = tid + j * 256;
            int r = f >> 4, c4 = (f & 15) << 2;
            *(float4*)&XSs[r][c4] = *(const float4*)(qkv_b + (size_t)(c0 + r)*2304 + 768 + c4);
        }
        __syncthreads();
        #pragma unroll 1
        for (int i = 0; i < 16; ++i) {
            int r = w * 16 + i;
            int n = c0 + r;
            float xk = XSs[r][lane];
            float z = b1s[lane];
            #pragma unroll
            for (int k2 = 0; k2 < 64; ++k2) z += XSs[r][k2] * W1s[k2][lane];
            float mu = wred(z) * 0.015625f;
            float zc = z - mu;
            float var = wred(zc * zc) * 0.015625f;
            float rstd = rsqrtf(var + 1e-6f);
            float xh = zc * rstd;
            float gm = gms[lane];
            float xv = qkv_b[(size_t)n * 2304 + 1536 + lane];
            float etav = eta_b[n];
            float gg = (gm * xh + bts[lane] - (xv - xk)) * gm;
            float s1 = wred(gg);
            float s2 = wred(gg * xh);
            float gf = (64.f * gg - s1 - xh * s2) * rstd * 0.015625f * etav * 0.0009765625f; // /(D)/(m)
            Gs[r][lane] = gf;
            gb1 += gf;
        }
        __syncthreads();
        // grad_W1 accumulation: acc[i] += XK[mm][dbase+i] * g[mm][e]
        #pragma unroll 4
        for (int mm = 0; mm < 64; ++mm) {
            float gv = Gs[mm][e];
            #pragma unroll
            for (int i2 = 0; i2 < 16; ++i2) acc[i2] += XSs[mm][dbase + i2] * gv;
        }
        __syncthreads();
    }

    // ---- W1n = W1 - grad_W1 ; b1n = b1 - grad_b1 ----
    gb1p[w][lane] = gb1;
    __syncthreads();
    #pragma unroll
    for (int i2 = 0; i2 < 16; ++i2) W1s[dbase + i2][e] -= acc[i2];
    if (tid < 64) bn1s[tid] = b1s[tid] - (gb1p[0][tid] + gb1p[1][tid] + gb1p[2][tid] + gb1p[3][tid]);
    __syncthreads();

    // ---- phase 2: out = XQ + LN(XQ@W1n + b1n) ----
    for (int c0 = 0; c0 < Ndim; c0 += 64) {
        #pragma unroll
        for (int j = 0; j < 4; ++j) {
            int f = tid + j * 256;
            int r = f >> 4, c4 = (f & 15) << 2;
            *(float4*)&XSs[r][c4] = *(const float4*)(qkv_b + (size_t)(c0 + r)*2304 + 0 + c4);
        }
        __syncthreads();
        #pragma unroll 1
        for (int i = 0; i < 16; ++i) {
            int r = w * 16 + i;
            int n = c0 + r;
            float xq = XSs[r][lane];
            float z = bn1s[lane];
            #pragma unroll
            for (int k2 = 0; k2 < 64; ++k2) z += XSs[r][k2] * W1s[k2][lane];
            float mu = wred(z) * 0.015625f;
            float zc = z - mu;
            float var = wred(zc * zc) * 0.015625f;
            float rstd = rsqrtf(var + 1e-6f);
            float xh = zc * rstd;
            inner[(size_t)(b * Ndim + n) * Cdim + h * 64 + lane] = xq + gms[lane] * xh + bts[lane];
        }
        __syncthreads();
    }
}

extern "C" void kernel_launch(void* const* d_in, const int* in_sizes, int n_in,
                              void* d_out, int out_size, void* d_ws, size_t ws_size,
                              hipStream_t stream) {
    const float* x     = (const float*)d_in[0];
    const float* qkvw  = (const float*)d_in[1];
    const float* qb    = (const float*)d_in[2];
    const float* vb    = (const float*)d_in[3];
    const float* pw    = (const float*)d_in[4];
    const float* pb    = (const float*)d_in[5];
    const float* lrw   = (const float*)d_in[6];
    const float* lrb   = (const float*)d_in[7];
    const float* gamma = (const float*)d_in[8];
    const float* beta  = (const float*)d_in[9];
    const float* W1    = (const float*)d_in[10];
    const float* b1    = (const float*)d_in[11];
    float* out = (float*)d_out;

    float* qkv   = (float*)d_ws;                         // 16384*2304 f32 = 144 MB
    float* eta   = qkv + (size_t)16384 * 2304;           // 196608 f32
    float* inner = eta + 196608;                         // 16384*768 f32 = 48 MB

    // 1) qkv = x @ qkv_weight^T + [q_bias, 0, v_bias]
    gemm_abt<0><<<dim3(Bdim*Ndim/64, 2304/64), 256, 0, stream>>>(
        x, qkvw, qb, vb, qkv, Bdim*Ndim, 2304, Cdim);
    // 2) eta = sigmoid(x . lrw + lrb) / 64
    eta_kernel<<<Bdim*Ndim, 256, 0, stream>>>(x, lrw, lrb, eta);
    // 3) TTT scan per (b,h)
    ttt_kernel<<<Bdim*Hdim, 256, 0, stream>>>(qkv, eta, W1, b1, gamma, beta, inner);
    // 4) out = inner @ proj_weight^T + proj_bias
    gemm_abt<1><<<dim3(Bdim*Ndim/64, Cdim/64), 256, 0, stream>>>(
        inner, pw, pb, nullptr, out, Bdim*Ndim, Cdim, Cdim);
}

// Round 5
// 854.665 us; speedup vs baseline: 2.3272x; 2.3272x over previous
//
#include <hip/hip_runtime.h>
#include <hip/hip_bf16.h>
#include <math.h>

// B=16, N=1024, C=768, H=12, HD=64, num_mini_batch=1 (m=1024)
// out = proj( TTT_scan( qkv(x) ) )
// R1: bf16 MFMA GEMMs (m97 structure: 128x128 tile, BK=32, global_load_lds w=16)
// R2-R4: identical resubmission (R1-R3 never ran — GPU acquisition timeouts)

#define Bdim 16
#define Ndim 1024
#define Cdim 768
#define Hdim 12
#define HDdim 64

typedef __hip_bfloat16 bf16;
typedef short short8 __attribute__((ext_vector_type(8)));   // 8 bf16 (4 VGPRs)
typedef short short4v __attribute__((ext_vector_type(4)));
typedef float f32x4 __attribute__((ext_vector_type(4)));

__device__ __forceinline__ float wred(float v) {
    #pragma unroll
    for (int o = 32; o > 0; o >>= 1) v += __shfl_xor(v, o);
    return v;
}

__device__ __forceinline__ unsigned short f2bf(float f) {
    __hip_bfloat16 h = __float2bfloat16(f);
    return *reinterpret_cast<unsigned short*>(&h);
}

__device__ __forceinline__ void gload_lds16(const bf16* g, bf16* l) {
    __builtin_amdgcn_global_load_lds(
        (const __attribute__((address_space(1))) void*)g,
        (__attribute__((address_space(3))) void*)l, 16, 0, 0);
}

// ---------------- cast fp32 -> bf16 (4 elems/thread) ----------------
__global__ __launch_bounds__(256) void cast_kernel(
    const float* __restrict__ in, unsigned short* __restrict__ out)
{
    int i = blockIdx.x * 256 + threadIdx.x;
    float4 v = ((const float4*)in)[i];
    short4v o;
    o.x = f2bf(v.x); o.y = f2bf(v.y); o.z = f2bf(v.z); o.w = f2bf(v.w);
    ((short4v*)out)[i] = o;
}

// ---------------- MFMA GEMM: C[M,N] = A[M,K] @ B[N,K]^T + bias ----------------
// A,B bf16 row-major (K contiguous). C fp32.
// BIAS_MODE 0: qkv bias = concat(q_bias, zeros, v_bias); 1: plain bias b0[col]
template<int BIAS_MODE>
__global__ __launch_bounds__(256) void gemm_bt_mfma(
    const bf16* __restrict__ A, const bf16* __restrict__ B,
    const float* __restrict__ b0, const float* __restrict__ b1v,
    float* __restrict__ C, int M, int N, int K)
{
    __shared__ bf16 As[128 * 32];
    __shared__ bf16 Bs[128 * 32];
    const int tid = threadIdx.x;
    const int wid = tid >> 6, lane = tid & 63;
    const int row0 = blockIdx.x * 128, col0 = blockIdx.y * 128;

    // staging: wave w, instr j covers 16 rows starting at (w*2+j)*16
    // lane l within chunk: row = l>>2, col8 = (l&3)*8  (lds dest = base + l*16B)
    const int srow = lane >> 2;
    const int scol = (lane & 3) * 8;
    const bf16* Ag[2]; const bf16* Bg[2];
    bf16* Al[2]; bf16* Bl[2];
    #pragma unroll
    for (int j = 0; j < 2; ++j) {
        int chunk = wid * 2 + j;                 // 0..7
        int r = chunk * 16 + srow;               // 0..127
        Ag[j] = A + (size_t)(row0 + r) * K + scol;
        Bg[j] = B + (size_t)(col0 + r) * K + scol;
        Al[j] = &As[chunk * 16 * 32];
        Bl[j] = &Bs[chunk * 16 * 32];
    }

    const int wm = (wid >> 1) * 64, wn = (wid & 1) * 64;
    const int fr = lane & 15;       // row (A) / col (B) within 16x16 frag
    const int fq = lane >> 4;       // k-quad
    f32x4 acc[4][4] = {};

    for (int k0 = 0; k0 < K; k0 += 32) {
        __syncthreads();
        #pragma unroll
        for (int j = 0; j < 2; ++j) {
            gload_lds16(Ag[j] + k0, Al[j]);
            gload_lds16(Bg[j] + k0, Bl[j]);
        }
        __syncthreads();
        short8 af[4], bfr[4];
        #pragma unroll
        for (int i = 0; i < 4; ++i) {
            af[i]  = *(const short8*)&As[(wm + i * 16 + fr) * 32 + fq * 8];
            bfr[i] = *(const short8*)&Bs[(wn + i * 16 + fr) * 32 + fq * 8];
        }
        #pragma unroll
        for (int mi = 0; mi < 4; ++mi)
            #pragma unroll
            for (int ni = 0; ni < 4; ++ni)
                acc[mi][ni] = __builtin_amdgcn_mfma_f32_16x16x32_bf16(
                    af[mi], bfr[ni], acc[mi][ni], 0, 0, 0);
    }

    // epilogue: D mapping col=lane&15, row=(lane>>4)*4+r
    #pragma unroll
    for (int ni = 0; ni < 4; ++ni) {
        int ccol = col0 + wn + ni * 16 + fr;
        float bias;
        if (BIAS_MODE == 0) bias = (ccol < 768) ? b0[ccol] : (ccol < 1536 ? 0.f : b1v[ccol - 1536]);
        else                bias = b0[ccol];
        #pragma unroll
        for (int mi = 0; mi < 4; ++mi) {
            #pragma unroll
            for (int r = 0; r < 4; ++r) {
                int crow = row0 + wm + mi * 16 + fq * 4 + r;
                C[(size_t)crow * N + ccol] = acc[mi][ni][r] + bias;
            }
        }
    }
}

// ---------------- eta: sigmoid(x . lrw_h + lrb_h)/64, [B,H,N] ----------------
__global__ __launch_bounds__(256) void eta_kernel(
    const float* __restrict__ x, const float* __restrict__ lrw,
    const float* __restrict__ lrb, float* __restrict__ eta)
{
    __shared__ float xs[768];
    const int bn = blockIdx.x;               // b*1024 + n
    const int tid = threadIdx.x, lane = tid & 63, w = tid >> 6;
    const float* xrow = x + (size_t)bn * Cdim;
    if (tid < 192) *(float4*)&xs[tid*4] = *(const float4*)&xrow[tid*4];
    __syncthreads();
    const int b = bn >> 10, n = bn & 1023;
    for (int h = w; h < Hdim; h += 4) {
        float p = 0.f;
        const float* wr = lrw + h * Cdim;
        #pragma unroll
        for (int j = 0; j < 12; ++j) p += xs[lane + j*64] * wr[lane + j*64];
        p = wred(p);
        if (lane == 0) {
            float v = p + lrb[h];
            eta[((size_t)b*Hdim + h)*Ndim + n] = (1.f / (1.f + expf(-v))) * 0.015625f; // sigmoid/64
        }
    }
}

// ---------------- TTT scan (single mini-batch): one block per (b,h) ----------------
__global__ __launch_bounds__(256) void ttt_kernel(
    const float* __restrict__ qkv,    // [B*N, 2304]  (q | k | v), col = which*768 + h*64 + d
    const float* __restrict__ eta,    // [B,H,N]
    const float* __restrict__ W1g,    // [H,64,64]
    const float* __restrict__ b1g,    // [H,64]
    const float* __restrict__ gammag, // [H,64]
    const float* __restrict__ betag,  // [H,64]
    unsigned short* __restrict__ inner) // bf16 [B*N, 768], col = h*64 + d
{
    const int bh = blockIdx.x;
    const int b = bh / Hdim, h = bh % Hdim;
    const int tid = threadIdx.x, lane = tid & 63, w = tid >> 6;
    const int e = lane, dbase = w * 16;

    __shared__ float W1s[64][64];
    __shared__ float XSs[64][64];
    __shared__ float Gs[64][64];
    __shared__ float b1s[64], gms[64], bts[64], bn1s[64];
    __shared__ float gb1p[4][64];

    for (int i = tid; i < 4096; i += 256) ((float*)W1s)[i] = W1g[h*4096 + i];
    if (tid < 64) {
        b1s[tid] = b1g[h*64 + tid];
        gms[tid] = gammag[h*64 + tid];
        bts[tid] = betag[h*64 + tid];
    }
    float acc[16];
    #pragma unroll
    for (int i = 0; i < 16; ++i) acc[i] = 0.f;
    float gb1 = 0.f;

    const float* qkv_b = qkv + (size_t)b * Ndim * 2304 + h * 64;
    const float* eta_b = eta + ((size_t)b * Hdim + h) * Ndim;
    __syncthreads();

    // ---- phase 1: Z1 = XK@W1 + b1 ; g = LN-L2-bwd ; accumulate grad_W1, grad_b1 ----
    for (int c0 = 0; c0 < Ndim; c0 += 64) {
        #pragma unroll
        for (int j = 0; j < 4; ++j) {
            int f = tid + j * 256;
            int r = f >> 4, c4 = (f & 15) << 2;
            *(float4*)&XSs[r][c4] = *(const float4*)(qkv_b + (size_t)(c0 + r)*2304 + 768 + c4);
        }
        __syncthreads();
        #pragma unroll 1
        for (int i = 0; i < 16; ++i) {
            int r = w * 16 + i;
            int n = c0 + r;
            float xk = XSs[r][lane];
            float z = b1s[lane];
            #pragma unroll
            for (int k2 = 0; k2 < 64; ++k2) z += XSs[r][k2] * W1s[k2][lane];
            float mu = wred(z) * 0.015625f;
            float zc = z - mu;
            float var = wred(zc * zc) * 0.015625f;
            float rstd = rsqrtf(var + 1e-6f);
            float xh = zc * rstd;
            float gm = gms[lane];
            float xv = qkv_b[(size_t)n * 2304 + 1536 + lane];
            float etav = eta_b[n];
            float gg = (gm * xh + bts[lane] - (xv - xk)) * gm;
            float s1 = wred(gg);
            float s2 = wred(gg * xh);
            float gf = (64.f * gg - s1 - xh * s2) * rstd * 0.015625f * etav * 0.0009765625f; // /(D)/(m)
            Gs[r][lane] = gf;
            gb1 += gf;
        }
        __syncthreads();
        #pragma unroll 4
        for (int mm = 0; mm < 64; ++mm) {
            float gv = Gs[mm][e];
            #pragma unroll
            for (int i2 = 0; i2 < 16; ++i2) acc[i2] += XSs[mm][dbase + i2] * gv;
        }
        __syncthreads();
    }

    // ---- W1n = W1 - grad_W1 ; b1n = b1 - grad_b1 ----
    gb1p[w][lane] = gb1;
    __syncthreads();
    #pragma unroll
    for (int i2 = 0; i2 < 16; ++i2) W1s[dbase + i2][e] -= acc[i2];
    if (tid < 64) bn1s[tid] = b1s[tid] - (gb1p[0][tid] + gb1p[1][tid] + gb1p[2][tid] + gb1p[3][tid]);
    __syncthreads();

    // ---- phase 2: out = XQ + LN(XQ@W1n + b1n) ----
    for (int c0 = 0; c0 < Ndim; c0 += 64) {
        #pragma unroll
        for (int j = 0; j < 4; ++j) {
            int f = tid + j * 256;
            int r = f >> 4, c4 = (f & 15) << 2;
            *(float4*)&XSs[r][c4] = *(const float4*)(qkv_b + (size_t)(c0 + r)*2304 + 0 + c4);
        }
        __syncthreads();
        #pragma unroll 1
        for (int i = 0; i < 16; ++i) {
            int r = w * 16 + i;
            int n = c0 + r;
            float xq = XSs[r][lane];
            float z = bn1s[lane];
            #pragma unroll
            for (int k2 = 0; k2 < 64; ++k2) z += XSs[r][k2] * W1s[k2][lane];
            float mu = wred(z) * 0.015625f;
            float zc = z - mu;
            float var = wred(zc * zc) * 0.015625f;
            float rstd = rsqrtf(var + 1e-6f);
            float xh = zc * rstd;
            inner[(size_t)(b * Ndim + n) * Cdim + h * 64 + lane] =
                f2bf(xq + gms[lane] * xh + bts[lane]);
        }
        __syncthreads();
    }
}

extern "C" void kernel_launch(void* const* d_in, const int* in_sizes, int n_in,
                              void* d_out, int out_size, void* d_ws, size_t ws_size,
                              hipStream_t stream) {
    const float* x     = (const float*)d_in[0];
    const float* qkvw  = (const float*)d_in[1];
    const float* qb    = (const float*)d_in[2];
    const float* vb    = (const float*)d_in[3];
    const float* pw    = (const float*)d_in[4];
    const float* pb    = (const float*)d_in[5];
    const float* lrw   = (const float*)d_in[6];
    const float* lrb   = (const float*)d_in[7];
    const float* gamma = (const float*)d_in[8];
    const float* beta  = (const float*)d_in[9];
    const float* W1    = (const float*)d_in[10];
    const float* b1    = (const float*)d_in[11];
    float* out = (float*)d_out;

    // workspace layout
    float* qkv = (float*)d_ws;                                  // 16384*2304 f32 = 144 MB
    float* eta = qkv + (size_t)16384 * 2304;                    // 196608 f32
    unsigned short* inner = (unsigned short*)(eta + 196608);    // bf16 16384*768 = 24 MB
    unsigned short* xb    = inner + (size_t)16384 * 768;        // bf16 x, 24 MB
    unsigned short* qkvwb = xb + (size_t)16384 * 768;           // bf16 qkv_weight, 3.4 MB
    unsigned short* pwb   = qkvwb + (size_t)2304 * 768;         // bf16 proj_weight, 1.1 MB

    // 0) casts to bf16
    cast_kernel<<<16384 * 768 / 1024, 256, 0, stream>>>(x, xb);
    cast_kernel<<<2304 * 768 / 1024, 256, 0, stream>>>(qkvw, qkvwb);
    cast_kernel<<<768 * 768 / 1024, 256, 0, stream>>>(pw, pwb);

    // 1) qkv = x @ qkv_weight^T + [q_bias, 0, v_bias]   (bf16 MFMA, fp32 out)
    gemm_bt_mfma<0><<<dim3(16384 / 128, 2304 / 128), 256, 0, stream>>>(
        (const bf16*)xb, (const bf16*)qkvwb, qb, vb, qkv, 16384, 2304, Cdim);

    // 2) eta = sigmoid(x . lrw + lrb) / 64   (fp32)
    eta_kernel<<<Bdim * Ndim, 256, 0, stream>>>(x, lrw, lrb, eta);

    // 3) TTT scan per (b,h)  (fp32 compute, bf16 inner out)
    ttt_kernel<<<Bdim * Hdim, 256, 0, stream>>>(qkv, eta, W1, b1, gamma, beta, inner);

    // 4) out = inner @ proj_weight^T + proj_bias   (bf16 MFMA, fp32 out)
    gemm_bt_mfma<1><<<dim3(16384 / 128, 768 / 128), 256, 0, stream>>>(
        (const bf16*)inner, (const bf16*)pwb, pb, nullptr, out, 16384, Cdim, Cdim);
}

// Round 8
// 479.614 us; speedup vs baseline: 4.1471x; 1.7820x over previous
//
#include <hip/hip_runtime.h>
#include <hip/hip_bf16.h>
#include <math.h>

// B=16, N=1024, C=768, H=12, HD=64, num_mini_batch=1 (m=1024)
// out = proj( TTT_scan( qkv(x) ) )
// R1: bf16 MFMA GEMMs (128x128 tile, BK=32, global_load_lds w=16)  -> 854us, ttt=606us
// R5: num_mini_batch==1 => no sequential scan. Split ttt into init/grad/apply,
//     shard each (b,h) over 8 token-chunks (192 -> 1536 blocks), grad via
//     device-scope fp32 atomicAdd into W1n/bn1. Same fp32 row math as R1.
// R6/R7: identical resubmission (R5/R6 never ran — GPU acquisition timeouts)

#define Bdim 16
#define Ndim 1024
#define Cdim 768
#define Hdim 12
#define HDdim 64
#define NCH 8          // token chunks per (b,h)
#define CH 128         // tokens per chunk

typedef __hip_bfloat16 bf16;
typedef short short8 __attribute__((ext_vector_type(8)));   // 8 bf16 (4 VGPRs)
typedef short short4v __attribute__((ext_vector_type(4)));
typedef float f32x4 __attribute__((ext_vector_type(4)));

__device__ __forceinline__ float wred(float v) {
    #pragma unroll
    for (int o = 32; o > 0; o >>= 1) v += __shfl_xor(v, o);
    return v;
}

__device__ __forceinline__ unsigned short f2bf(float f) {
    __hip_bfloat16 h = __float2bfloat16(f);
    return *reinterpret_cast<unsigned short*>(&h);
}

__device__ __forceinline__ void gload_lds16(const bf16* g, bf16* l) {
    __builtin_amdgcn_global_load_lds(
        (const __attribute__((address_space(1))) void*)g,
        (__attribute__((address_space(3))) void*)l, 16, 0, 0);
}

// ---------------- cast fp32 -> bf16 (4 elems/thread) ----------------
__global__ __launch_bounds__(256) void cast_kernel(
    const float* __restrict__ in, unsigned short* __restrict__ out)
{
    int i = blockIdx.x * 256 + threadIdx.x;
    float4 v = ((const float4*)in)[i];
    short4v o;
    o.x = f2bf(v.x); o.y = f2bf(v.y); o.z = f2bf(v.z); o.w = f2bf(v.w);
    ((short4v*)out)[i] = o;
}

// ---------------- MFMA GEMM: C[M,N] = A[M,K] @ B[N,K]^T + bias ----------------
template<int BIAS_MODE>
__global__ __launch_bounds__(256) void gemm_bt_mfma(
    const bf16* __restrict__ A, const bf16* __restrict__ B,
    const float* __restrict__ b0, const float* __restrict__ b1v,
    float* __restrict__ C, int M, int N, int K)
{
    __shared__ bf16 As[128 * 32];
    __shared__ bf16 Bs[128 * 32];
    const int tid = threadIdx.x;
    const int wid = tid >> 6, lane = tid & 63;
    const int row0 = blockIdx.x * 128, col0 = blockIdx.y * 128;

    const int srow = lane >> 2;
    const int scol = (lane & 3) * 8;
    const bf16* Ag[2]; const bf16* Bg[2];
    bf16* Al[2]; bf16* Bl[2];
    #pragma unroll
    for (int j = 0; j < 2; ++j) {
        int chunk = wid * 2 + j;                 // 0..7
        int r = chunk * 16 + srow;               // 0..127
        Ag[j] = A + (size_t)(row0 + r) * K + scol;
        Bg[j] = B + (size_t)(col0 + r) * K + scol;
        Al[j] = &As[chunk * 16 * 32];
        Bl[j] = &Bs[chunk * 16 * 32];
    }

    const int wm = (wid >> 1) * 64, wn = (wid & 1) * 64;
    const int fr = lane & 15;
    const int fq = lane >> 4;
    f32x4 acc[4][4] = {};

    for (int k0 = 0; k0 < K; k0 += 32) {
        __syncthreads();
        #pragma unroll
        for (int j = 0; j < 2; ++j) {
            gload_lds16(Ag[j] + k0, Al[j]);
            gload_lds16(Bg[j] + k0, Bl[j]);
        }
        __syncthreads();
        short8 af[4], bfr[4];
        #pragma unroll
        for (int i = 0; i < 4; ++i) {
            af[i]  = *(const short8*)&As[(wm + i * 16 + fr) * 32 + fq * 8];
            bfr[i] = *(const short8*)&Bs[(wn + i * 16 + fr) * 32 + fq * 8];
        }
        #pragma unroll
        for (int mi = 0; mi < 4; ++mi)
            #pragma unroll
            for (int ni = 0; ni < 4; ++ni)
                acc[mi][ni] = __builtin_amdgcn_mfma_f32_16x16x32_bf16(
                    af[mi], bfr[ni], acc[mi][ni], 0, 0, 0);
    }

    #pragma unroll
    for (int ni = 0; ni < 4; ++ni) {
        int ccol = col0 + wn + ni * 16 + fr;
        float bias;
        if (BIAS_MODE == 0) bias = (ccol < 768) ? b0[ccol] : (ccol < 1536 ? 0.f : b1v[ccol - 1536]);
        else                bias = b0[ccol];
        #pragma unroll
        for (int mi = 0; mi < 4; ++mi) {
            #pragma unroll
            for (int r = 0; r < 4; ++r) {
                int crow = row0 + wm + mi * 16 + fq * 4 + r;
                C[(size_t)crow * N + ccol] = acc[mi][ni][r] + bias;
            }
        }
    }
}

// ---------------- eta: sigmoid(x . lrw_h + lrb_h)/64, [B,H,N] ----------------
__global__ __launch_bounds__(256) void eta_kernel(
    const float* __restrict__ x, const float* __restrict__ lrw,
    const float* __restrict__ lrb, float* __restrict__ eta)
{
    __shared__ float xs[768];
    const int bn = blockIdx.x;
    const int tid = threadIdx.x, lane = tid & 63, w = tid >> 6;
    const float* xrow = x + (size_t)bn * Cdim;
    if (tid < 192) *(float4*)&xs[tid*4] = *(const float4*)&xrow[tid*4];
    __syncthreads();
    const int b = bn >> 10, n = bn & 1023;
    for (int h = w; h < Hdim; h += 4) {
        float p = 0.f;
        const float* wr = lrw + h * Cdim;
        #pragma unroll
        for (int j = 0; j < 12; ++j) p += xs[lane + j*64] * wr[lane + j*64];
        p = wred(p);
        if (lane == 0) {
            float v = p + lrb[h];
            eta[((size_t)b*Hdim + h)*Ndim + n] = (1.f / (1.f + expf(-v))) * 0.015625f;
        }
    }
}

// ---------------- ttt_init: W1n = W1 (broadcast), bn1 = b1 ----------------
__global__ __launch_bounds__(256) void ttt_init(
    const float* __restrict__ W1g, const float* __restrict__ b1g,
    float* __restrict__ W1n, float* __restrict__ bn1)
{
    const int bh = blockIdx.x, h = bh % Hdim, tid = threadIdx.x;
    #pragma unroll
    for (int j = 0; j < 16; ++j)
        W1n[(size_t)bh * 4096 + j * 256 + tid] = W1g[h * 4096 + j * 256 + tid];
    if (tid < 64) bn1[bh * 64 + tid] = b1g[h * 64 + tid];
}

// ---------------- ttt_grad: per (b,h,chunk) accumulate -grad into W1n/bn1 ----------------
__global__ __launch_bounds__(256) void ttt_grad(
    const float* __restrict__ qkv,    // [B*N, 2304], col = which*768 + h*64 + d
    const float* __restrict__ eta,    // [B,H,N]
    const float* __restrict__ W1g,    // [H,64,64]  (original W1 for Z1)
    const float* __restrict__ b1g,    // [H,64]
    const float* __restrict__ gammag, const float* __restrict__ betag,
    float* __restrict__ W1n,          // [B*H,64,64] pre-initialized to W1
    float* __restrict__ bn1)          // [B*H,64]    pre-initialized to b1
{
    const int bh = blockIdx.x;
    const int b = bh / Hdim, h = bh % Hdim;
    const int c0base = blockIdx.y * CH;
    const int tid = threadIdx.x, lane = tid & 63, w = tid >> 6;
    const int e = lane, dbase = w * 16;

    __shared__ float W1s[64][64];
    __shared__ float XSs[64][64];
    __shared__ float Gs[64][64];
    __shared__ float b1s[64], gms[64], bts[64];
    __shared__ float gb1p[4][64];

    for (int i = tid; i < 4096; i += 256) ((float*)W1s)[i] = W1g[h*4096 + i];
    if (tid < 64) {
        b1s[tid] = b1g[h*64 + tid];
        gms[tid] = gammag[h*64 + tid];
        bts[tid] = betag[h*64 + tid];
    }
    float acc[16];
    #pragma unroll
    for (int i = 0; i < 16; ++i) acc[i] = 0.f;
    float gb1 = 0.f;

    const float* qkv_b = qkv + (size_t)b * Ndim * 2304 + h * 64;
    const float* eta_b = eta + ((size_t)b * Hdim + h) * Ndim;
    __syncthreads();

    for (int half = 0; half < CH / 64; ++half) {
        const int c0 = c0base + half * 64;
        #pragma unroll
        for (int j = 0; j < 4; ++j) {
            int f = tid + j * 256;
            int r = f >> 4, c4 = (f & 15) << 2;
            *(float4*)&XSs[r][c4] = *(const float4*)(qkv_b + (size_t)(c0 + r)*2304 + 768 + c4);
        }
        __syncthreads();
        #pragma unroll 1
        for (int i = 0; i < 16; ++i) {
            int r = w * 16 + i;
            int n = c0 + r;
            float xk = XSs[r][lane];
            float z = b1s[lane];
            #pragma unroll
            for (int k2 = 0; k2 < 64; ++k2) z += XSs[r][k2] * W1s[k2][lane];
            float mu = wred(z) * 0.015625f;
            float zc = z - mu;
            float var = wred(zc * zc) * 0.015625f;
            float rstd = rsqrtf(var + 1e-6f);
            float xh = zc * rstd;
            float gm = gms[lane];
            float xv = qkv_b[(size_t)n * 2304 + 1536 + lane];
            float etav = eta_b[n];
            float gg = (gm * xh + bts[lane] - (xv - xk)) * gm;
            float s1 = wred(gg);
            float s2 = wred(gg * xh);
            float gf = (64.f * gg - s1 - xh * s2) * rstd * 0.015625f * etav * 0.0009765625f;
            Gs[r][lane] = gf;
            gb1 += gf;
        }
        __syncthreads();
        #pragma unroll 4
        for (int mm = 0; mm < 64; ++mm) {
            float gv = Gs[mm][e];
            #pragma unroll
            for (int i2 = 0; i2 < 16; ++i2) acc[i2] += XSs[mm][dbase + i2] * gv;
        }
        __syncthreads();
    }

    // accumulate -grad into global W1n/bn1 (device-scope atomics; 8-way contention)
    #pragma unroll
    for (int i2 = 0; i2 < 16; ++i2)
        atomicAdd(&W1n[(size_t)bh * 4096 + (dbase + i2) * 64 + e], -acc[i2]);
    gb1p[w][lane] = gb1;
    __syncthreads();
    if (tid < 64) {
        float s = gb1p[0][tid] + gb1p[1][tid] + gb1p[2][tid] + gb1p[3][tid];
        atomicAdd(&bn1[bh * 64 + tid], -s);
    }
}

// ---------------- ttt_apply: out = XQ + LN(XQ@W1n + bn1) ----------------
__global__ __launch_bounds__(256) void ttt_apply(
    const float* __restrict__ qkv,
    const float* __restrict__ W1n, const float* __restrict__ bn1,
    const float* __restrict__ gammag, const float* __restrict__ betag,
    unsigned short* __restrict__ inner)   // bf16 [B*N, 768]
{
    const int bh = blockIdx.x;
    const int b = bh / Hdim, h = bh % Hdim;
    const int c0base = blockIdx.y * CH;
    const int tid = threadIdx.x, lane = tid & 63, w = tid >> 6;

    __shared__ float W1s[64][64];
    __shared__ float XSs[64][64];
    __shared__ float bn1s[64], gms[64], bts[64];

    for (int i = tid; i < 4096; i += 256) ((float*)W1s)[i] = W1n[(size_t)bh*4096 + i];
    if (tid < 64) {
        bn1s[tid] = bn1[bh*64 + tid];
        gms[tid] = gammag[h*64 + tid];
        bts[tid] = betag[h*64 + tid];
    }
    const float* qkv_b = qkv + (size_t)b * Ndim * 2304 + h * 64;
    __syncthreads();

    for (int half = 0; half < CH / 64; ++half) {
        const int c0 = c0base + half * 64;
        #pragma unroll
        for (int j = 0; j < 4; ++j) {
            int f = tid + j * 256;
            int r = f >> 4, c4 = (f & 15) << 2;
            *(float4*)&XSs[r][c4] = *(const float4*)(qkv_b + (size_t)(c0 + r)*2304 + 0 + c4);
        }
        __syncthreads();
        #pragma unroll 1
        for (int i = 0; i < 16; ++i) {
            int r = w * 16 + i;
            int n = c0 + r;
            float xq = XSs[r][lane];
            float z = bn1s[lane];
            #pragma unroll
            for (int k2 = 0; k2 < 64; ++k2) z += XSs[r][k2] * W1s[k2][lane];
            float mu = wred(z) * 0.015625f;
            float zc = z - mu;
            float var = wred(zc * zc) * 0.015625f;
            float rstd = rsqrtf(var + 1e-6f);
            float xh = zc * rstd;
            inner[(size_t)(b * Ndim + n) * Cdim + h * 64 + lane] =
                f2bf(xq + gms[lane] * xh + bts[lane]);
        }
        __syncthreads();
    }
}

extern "C" void kernel_launch(void* const* d_in, const int* in_sizes, int n_in,
                              void* d_out, int out_size, void* d_ws, size_t ws_size,
                              hipStream_t stream) {
    const float* x     = (const float*)d_in[0];
    const float* qkvw  = (const float*)d_in[1];
    const float* qb    = (const float*)d_in[2];
    const float* vb    = (const float*)d_in[3];
    const float* pw    = (const float*)d_in[4];
    const float* pb    = (const float*)d_in[5];
    const float* lrw   = (const float*)d_in[6];
    const float* lrb   = (const float*)d_in[7];
    const float* gamma = (const float*)d_in[8];
    const float* beta  = (const float*)d_in[9];
    const float* W1    = (const float*)d_in[10];
    const float* b1    = (const float*)d_in[11];
    float* out = (float*)d_out;

    // workspace layout
    float* qkv = (float*)d_ws;                                  // 16384*2304 f32 = 151 MB
    float* eta = qkv + (size_t)16384 * 2304;                    // 196608 f32
    unsigned short* inner = (unsigned short*)(eta + 196608);    // bf16 16384*768 = 25 MB
    unsigned short* xb    = inner + (size_t)16384 * 768;        // bf16 x, 25 MB
    unsigned short* qkvwb = xb + (size_t)16384 * 768;           // bf16 qkv_weight
    unsigned short* pwb   = qkvwb + (size_t)2304 * 768;         // bf16 proj_weight
    float* W1n = (float*)(pwb + (size_t)768 * 768);             // [192,64,64] f32 = 3.1 MB
    float* bn1 = W1n + (size_t)192 * 4096;                      // [192,64] f32

    // 0) casts to bf16
    cast_kernel<<<16384 * 768 / 1024, 256, 0, stream>>>(x, xb);
    cast_kernel<<<2304 * 768 / 1024, 256, 0, stream>>>(qkvw, qkvwb);
    cast_kernel<<<768 * 768 / 1024, 256, 0, stream>>>(pw, pwb);

    // 1) qkv = x @ qkv_weight^T + [q_bias, 0, v_bias]
    gemm_bt_mfma<0><<<dim3(16384 / 128, 2304 / 128), 256, 0, stream>>>(
        (const bf16*)xb, (const bf16*)qkvwb, qb, vb, qkv, 16384, 2304, Cdim);

    // 2) eta
    eta_kernel<<<Bdim * Ndim, 256, 0, stream>>>(x, lrw, lrb, eta);

    // 3) ttt: init -> grad (sharded, atomic) -> apply (sharded)
    ttt_init<<<Bdim * Hdim, 256, 0, stream>>>(W1, b1, W1n, bn1);
    ttt_grad<<<dim3(Bdim * Hdim, NCH), 256, 0, stream>>>(
        qkv, eta, W1, b1, gamma, beta, W1n, bn1);
    ttt_apply<<<dim3(Bdim * Hdim, NCH), 256, 0, stream>>>(
        qkv, W1n, bn1, gamma, beta, inner);

    // 4) out = inner @ proj_weight^T + proj_bias
    gemm_bt_mfma<1><<<dim3(16384 / 128, 768 / 128), 256, 0, stream>>>(
        (const bf16*)inner, (const bf16*)pwb, pb, nullptr, out, 16384, Cdim, Cdim);
}

// Round 9
// 425.328 us; speedup vs baseline: 4.6764x; 1.1276x over previous
//
#include <hip/hip_runtime.h>
#include <hip/hip_bf16.h>
#include <math.h>

// B=16, N=1024, C=768, H=12, HD=64, num_mini_batch=1 (m=1024)
// out = proj( TTT_scan( qkv(x) ) )
// R1: bf16 MFMA GEMMs (128x128 tile, BK=32, global_load_lds w=16)  -> 854us, ttt=606us
// R5: ttt split init/grad/apply, 8 chunks/(b,h), atomicAdd merge    -> 479.6us, grad=150us
// R8: MFMA-ize ttt inner matmuls (Z1, grad_W1, Z_bar) via bf16 16x16x32;
//     LN/target math stays fp32 (targets read f32 from global, L2-hot).
//     LDS transposed-operand layout: row stride 72 bf16 (144B, 16B-aligned).

#define Bdim 16
#define Ndim 1024
#define Cdim 768
#define Hdim 12
#define HDdim 64
#define NCH 8          // token chunks per (b,h)
#define CH 128         // tokens per chunk
#define LSTR 72        // LDS row stride in bf16 elems (144B)

typedef __hip_bfloat16 bf16;
typedef short short8 __attribute__((ext_vector_type(8)));   // 8 bf16 (4 VGPRs)
typedef short short4v __attribute__((ext_vector_type(4)));
typedef float f32x4 __attribute__((ext_vector_type(4)));

__device__ __forceinline__ float wred(float v) {
    #pragma unroll
    for (int o = 32; o > 0; o >>= 1) v += __shfl_xor(v, o);
    return v;
}

__device__ __forceinline__ unsigned short f2bf(float f) {
    __hip_bfloat16 h = __float2bfloat16(f);
    return *reinterpret_cast<unsigned short*>(&h);
}

__device__ __forceinline__ float bf2f(unsigned short u) {
    unsigned int x = ((unsigned int)u) << 16;
    return __uint_as_float(x);
}

__device__ __forceinline__ void gload_lds16(const bf16* g, bf16* l) {
    __builtin_amdgcn_global_load_lds(
        (const __attribute__((address_space(1))) void*)g,
        (__attribute__((address_space(3))) void*)l, 16, 0, 0);
}

// ---------------- cast fp32 -> bf16 (4 elems/thread) ----------------
__global__ __launch_bounds__(256) void cast_kernel(
    const float* __restrict__ in, unsigned short* __restrict__ out)
{
    int i = blockIdx.x * 256 + threadIdx.x;
    float4 v = ((const float4*)in)[i];
    short4v o;
    o.x = f2bf(v.x); o.y = f2bf(v.y); o.z = f2bf(v.z); o.w = f2bf(v.w);
    ((short4v*)out)[i] = o;
}

// ---------------- MFMA GEMM: C[M,N] = A[M,K] @ B[N,K]^T + bias ----------------
template<int BIAS_MODE>
__global__ __launch_bounds__(256) void gemm_bt_mfma(
    const bf16* __restrict__ A, const bf16* __restrict__ B,
    const float* __restrict__ b0, const float* __restrict__ b1v,
    float* __restrict__ C, int M, int N, int K)
{
    __shared__ bf16 As[128 * 32];
    __shared__ bf16 Bs[128 * 32];
    const int tid = threadIdx.x;
    const int wid = tid >> 6, lane = tid & 63;
    const int row0 = blockIdx.x * 128, col0 = blockIdx.y * 128;

    const int srow = lane >> 2;
    const int scol = (lane & 3) * 8;
    const bf16* Ag[2]; const bf16* Bg[2];
    bf16* Al[2]; bf16* Bl[2];
    #pragma unroll
    for (int j = 0; j < 2; ++j) {
        int chunk = wid * 2 + j;
        int r = chunk * 16 + srow;
        Ag[j] = A + (size_t)(row0 + r) * K + scol;
        Bg[j] = B + (size_t)(col0 + r) * K + scol;
        Al[j] = &As[chunk * 16 * 32];
        Bl[j] = &Bs[chunk * 16 * 32];
    }

    const int wm = (wid >> 1) * 64, wn = (wid & 1) * 64;
    const int fr = lane & 15;
    const int fq = lane >> 4;
    f32x4 acc[4][4] = {};

    for (int k0 = 0; k0 < K; k0 += 32) {
        __syncthreads();
        #pragma unroll
        for (int j = 0; j < 2; ++j) {
            gload_lds16(Ag[j] + k0, Al[j]);
            gload_lds16(Bg[j] + k0, Bl[j]);
        }
        __syncthreads();
        short8 af[4], bfr[4];
        #pragma unroll
        for (int i = 0; i < 4; ++i) {
            af[i]  = *(const short8*)&As[(wm + i * 16 + fr) * 32 + fq * 8];
            bfr[i] = *(const short8*)&Bs[(wn + i * 16 + fr) * 32 + fq * 8];
        }
        #pragma unroll
        for (int mi = 0; mi < 4; ++mi)
            #pragma unroll
            for (int ni = 0; ni < 4; ++ni)
                acc[mi][ni] = __builtin_amdgcn_mfma_f32_16x16x32_bf16(
                    af[mi], bfr[ni], acc[mi][ni], 0, 0, 0);
    }

    #pragma unroll
    for (int ni = 0; ni < 4; ++ni) {
        int ccol = col0 + wn + ni * 16 + fr;
        float bias;
        if (BIAS_MODE == 0) bias = (ccol < 768) ? b0[ccol] : (ccol < 1536 ? 0.f : b1v[ccol - 1536]);
        else                bias = b0[ccol];
        #pragma unroll
        for (int mi = 0; mi < 4; ++mi) {
            #pragma unroll
            for (int r = 0; r < 4; ++r) {
                int crow = row0 + wm + mi * 16 + fq * 4 + r;
                C[(size_t)crow * N + ccol] = acc[mi][ni][r] + bias;
            }
        }
    }
}

// ---------------- eta: sigmoid(x . lrw_h + lrb_h)/64, [B,H,N] ----------------
__global__ __launch_bounds__(256) void eta_kernel(
    const float* __restrict__ x, const float* __restrict__ lrw,
    const float* __restrict__ lrb, float* __restrict__ eta)
{
    __shared__ float xs[768];
    const int bn = blockIdx.x;
    const int tid = threadIdx.x, lane = tid & 63, w = tid >> 6;
    const float* xrow = x + (size_t)bn * Cdim;
    if (tid < 192) *(float4*)&xs[tid*4] = *(const float4*)&xrow[tid*4];
    __syncthreads();
    const int b = bn >> 10, n = bn & 1023;
    for (int h = w; h < Hdim; h += 4) {
        float p = 0.f;
        const float* wr = lrw + h * Cdim;
        #pragma unroll
        for (int j = 0; j < 12; ++j) p += xs[lane + j*64] * wr[lane + j*64];
        p = wred(p);
        if (lane == 0) {
            float v = p + lrb[h];
            eta[((size_t)b*Hdim + h)*Ndim + n] = (1.f / (1.f + expf(-v))) * 0.015625f;
        }
    }
}

// ---------------- ttt_init: W1n = W1 (broadcast), bn1 = b1 ----------------
__global__ __launch_bounds__(256) void ttt_init(
    const float* __restrict__ W1g, const float* __restrict__ b1g,
    float* __restrict__ W1n, float* __restrict__ bn1)
{
    const int bh = blockIdx.x, h = bh % Hdim, tid = threadIdx.x;
    #pragma unroll
    for (int j = 0; j < 16; ++j)
        W1n[(size_t)bh * 4096 + j * 256 + tid] = W1g[h * 4096 + j * 256 + tid];
    if (tid < 64) bn1[bh * 64 + tid] = b1g[h * 64 + tid];
}

// ---------------- ttt_grad (MFMA): per (b,h,chunk) accumulate -grad ----------------
// Z1^T[e][t] = mfma(W1T, XK);  LN rows fp32;  gradW1^T[e][d] = mfma(G^T, XK^T)
__global__ __launch_bounds__(256) void ttt_grad(
    const float* __restrict__ qkv,    // [B*N, 2304], col = which*768 + h*64 + d
    const float* __restrict__ eta,    // [B,H,N]
    const float* __restrict__ W1g,    // [H,64,64]  (d-major: W1[d][e])
    const float* __restrict__ b1g,
    const float* __restrict__ gammag, const float* __restrict__ betag,
    float* __restrict__ W1n,          // [B*H,64,64] pre-init W1
    float* __restrict__ bn1)          // [B*H,64]    pre-init b1
{
    const int bh = blockIdx.x;
    const int b = bh / Hdim, h = bh % Hdim;
    const int c0base = blockIdx.y * CH;
    const int tid = threadIdx.x, lane = tid & 63, w = tid >> 6;
    const int fr = lane & 15, fq = lane >> 4;

    __shared__ __align__(16) unsigned short XKs [64 * LSTR];  // [t][d]
    __shared__ __align__(16) unsigned short XKTs[64 * LSTR];  // [d][t]
    __shared__ __align__(16) unsigned short W1Ts[64 * LSTR];  // [e][d]
    __shared__ __align__(16) unsigned short Gst [64 * LSTR];  // [e][t]
    __shared__ __align__(16) unsigned short Z1s [64 * LSTR];  // [t][e] (bf16 Z1)
    __shared__ float b1s[64], gms[64], bts[64];
    __shared__ float gb1p[4][64];

    // stage W1^T (once): W1Ts[e][d] = W1[d][e]
    for (int i = tid; i < 4096; i += 256) {
        int d = i >> 6, e = i & 63;
        W1Ts[e * LSTR + d] = f2bf(W1g[h * 4096 + i]);
    }
    if (tid < 64) {
        b1s[tid] = b1g[h*64 + tid];
        gms[tid] = gammag[h*64 + tid];
        bts[tid] = betag[h*64 + tid];
    }
    f32x4 gacc[4] = {};
    float gb1 = 0.f;

    const float* qkv_b = qkv + (size_t)b * Ndim * 2304 + h * 64;
    const float* eta_b = eta + ((size_t)b * Hdim + h) * Ndim;
    __syncthreads();

    #pragma unroll 1
    for (int half = 0; half < 2; ++half) {
        const int c0 = c0base + half * 64;
        // ---- stage XK (natural + transposed), bf16 ----
        #pragma unroll
        for (int j = 0; j < 4; ++j) {
            int f = tid + j * 256;
            int r = f >> 4, c4 = (f & 15) << 2;
            float4 v = *(const float4*)(qkv_b + (size_t)(c0 + r)*2304 + 768 + c4);
            unsigned short u0 = f2bf(v.x), u1 = f2bf(v.y), u2 = f2bf(v.z), u3 = f2bf(v.w);
            short4v sv; sv.x = (short)u0; sv.y = (short)u1; sv.z = (short)u2; sv.w = (short)u3;
            *(short4v*)&XKs[r * LSTR + c4] = sv;
            XKTs[(c4+0) * LSTR + r] = u0;
            XKTs[(c4+1) * LSTR + r] = u1;
            XKTs[(c4+2) * LSTR + r] = u2;
            XKTs[(c4+3) * LSTR + r] = u3;
        }
        __syncthreads();
        // ---- Z1^T[e][t] = sum_d W1T[e][d] * XK[t][d]; wave w: e-strip w*16 ----
        {
            short8 a0 = *(const short8*)&W1Ts[(w*16 + fr) * LSTR + 0];
            short8 a1 = *(const short8*)&W1Ts[(w*16 + fr) * LSTR + 32 + fq*8 - fq*8 + fq*8]; // placeholder avoided below
            a1 = *(const short8*)&W1Ts[(w*16 + fr) * LSTR + 32 + fq*8];
            a0 = *(const short8*)&W1Ts[(w*16 + fr) * LSTR + 0  + fq*8];
            f32x4 zacc[4] = {};
            #pragma unroll
            for (int nt = 0; nt < 4; ++nt) {
                short8 b0 = *(const short8*)&XKs[(nt*16 + fr) * LSTR + 0  + fq*8];
                short8 b1_ = *(const short8*)&XKs[(nt*16 + fr) * LSTR + 32 + fq*8];
                zacc[nt] = __builtin_amdgcn_mfma_f32_16x16x32_bf16(a0, b0, zacc[nt], 0, 0, 0);
                zacc[nt] = __builtin_amdgcn_mfma_f32_16x16x32_bf16(a1, b1_, zacc[nt], 0, 0, 0);
            }
            #pragma unroll
            for (int nt = 0; nt < 4; ++nt)
                #pragma unroll
                for (int rr = 0; rr < 4; ++rr)
                    Z1s[(nt*16 + fr) * LSTR + (w*16 + fq*4 + rr)] = f2bf(zacc[nt][rr]);
        }
        __syncthreads();
        // ---- LN rows (fp32), wave w: rows [w*16, w*16+16) ----
        float xkr[16], xvr[16], etr[16];
        #pragma unroll
        for (int i = 0; i < 16; ++i) {
            int n = c0 + w*16 + i;
            xkr[i] = qkv_b[(size_t)n * 2304 + 768 + lane];
            xvr[i] = qkv_b[(size_t)n * 2304 + 1536 + lane];
            etr[i] = eta_b[n];
        }
        #pragma unroll
        for (int i = 0; i < 16; ++i) {
            int r = w*16 + i;
            float z = bf2f(Z1s[r * LSTR + lane]) + b1s[lane];
            float mu = wred(z) * 0.015625f;
            float zc = z - mu;
            float var = wred(zc * zc) * 0.015625f;
            float rstd = rsqrtf(var + 1e-6f);
            float xh = zc * rstd;
            float gm = gms[lane];
            float gg = (gm * xh + bts[lane] - (xvr[i] - xkr[i])) * gm;
            float s1 = wred(gg);
            float s2 = wred(gg * xh);
            float gf = (64.f * gg - s1 - xh * s2) * rstd * 0.015625f * etr[i] * 0.0009765625f;
            gb1 += gf;
            Gst[lane * LSTR + r] = f2bf(gf);
        }
        __syncthreads();
        // ---- gradW1^T[e][d] += sum_t G[t][e] * XK[t][d]; wave w: e-strip ----
        {
            short8 a0 = *(const short8*)&Gst[(w*16 + fr) * LSTR + 0  + fq*8];
            short8 a1 = *(const short8*)&Gst[(w*16 + fr) * LSTR + 32 + fq*8];
            #pragma unroll
            for (int nt = 0; nt < 4; ++nt) {
                short8 b0 = *(const short8*)&XKTs[(nt*16 + fr) * LSTR + 0  + fq*8];
                short8 b1_ = *(const short8*)&XKTs[(nt*16 + fr) * LSTR + 32 + fq*8];
                gacc[nt] = __builtin_amdgcn_mfma_f32_16x16x32_bf16(a0, b0, gacc[nt], 0, 0, 0);
                gacc[nt] = __builtin_amdgcn_mfma_f32_16x16x32_bf16(a1, b1_, gacc[nt], 0, 0, 0);
            }
        }
        __syncthreads();   // protect restage of XKs/XKTs/Gst/Z1s
    }

    // ---- finalize: atomic -grad into W1n (elem grad_W1[d][e] = D[e][d]) ----
    #pragma unroll
    for (int nt = 0; nt < 4; ++nt) {
        int d = nt*16 + fr;
        #pragma unroll
        for (int rr = 0; rr < 4; ++rr) {
            int e = w*16 + fq*4 + rr;
            atomicAdd(&W1n[(size_t)bh * 4096 + d * 64 + e], -gacc[nt][rr]);
        }
    }
    gb1p[w][lane] = gb1;
    __syncthreads();
    if (tid < 64) {
        float s = gb1p[0][tid] + gb1p[1][tid] + gb1p[2][tid] + gb1p[3][tid];
        atomicAdd(&bn1[bh * 64 + tid], -s);
    }
}

// ---------------- ttt_apply (MFMA): inner = XQ + LN(XQ@W1n + bn1) ----------------
__global__ __launch_bounds__(256) void ttt_apply(
    const float* __restrict__ qkv,
    const float* __restrict__ W1n, const float* __restrict__ bn1,
    const float* __restrict__ gammag, const float* __restrict__ betag,
    unsigned short* __restrict__ inner)   // bf16 [B*N, 768]
{
    const int bh = blockIdx.x;
    const int b = bh / Hdim, h = bh % Hdim;
    const int c0base = blockIdx.y * CH;
    const int tid = threadIdx.x, lane = tid & 63, w = tid >> 6;
    const int fr = lane & 15, fq = lane >> 4;

    __shared__ __align__(16) unsigned short XQs  [64 * LSTR];  // [t][d]
    __shared__ __align__(16) unsigned short W1nTs[64 * LSTR];  // [e][d]
    __shared__ __align__(16) unsigned short Z1s  [64 * LSTR];  // [t][e]
    __shared__ float bn1s[64], gms[64], bts[64];

    for (int i = tid; i < 4096; i += 256) {
        int d = i >> 6, e = i & 63;
        W1nTs[e * LSTR + d] = f2bf(W1n[(size_t)bh * 4096 + i]);
    }
    if (tid < 64) {
        bn1s[tid] = bn1[bh*64 + tid];
        gms[tid] = gammag[h*64 + tid];
        bts[tid] = betag[h*64 + tid];
    }
    const float* qkv_b = qkv + (size_t)b * Ndim * 2304 + h * 64;
    __syncthreads();

    #pragma unroll 1
    for (int half = 0; half < 2; ++half) {
        const int c0 = c0base + half * 64;
        // ---- stage XQ bf16 ----
        #pragma unroll
        for (int j = 0; j < 4; ++j) {
            int f = tid + j * 256;
            int r = f >> 4, c4 = (f & 15) << 2;
            float4 v = *(const float4*)(qkv_b + (size_t)(c0 + r)*2304 + 0 + c4);
            short4v sv; sv.x = (short)f2bf(v.x); sv.y = (short)f2bf(v.y);
            sv.z = (short)f2bf(v.z); sv.w = (short)f2bf(v.w);
            *(short4v*)&XQs[r * LSTR + c4] = sv;
        }
        __syncthreads();
        // ---- Z^T[e][t] = sum_d W1nT[e][d] * XQ[t][d] ----
        {
            short8 a0 = *(const short8*)&W1nTs[(w*16 + fr) * LSTR + 0  + fq*8];
            short8 a1 = *(const short8*)&W1nTs[(w*16 + fr) * LSTR + 32 + fq*8];
            f32x4 zacc[4] = {};
            #pragma unroll
            for (int nt = 0; nt < 4; ++nt) {
                short8 b0 = *(const short8*)&XQs[(nt*16 + fr) * LSTR + 0  + fq*8];
                short8 b1_ = *(const short8*)&XQs[(nt*16 + fr) * LSTR + 32 + fq*8];
                zacc[nt] = __builtin_amdgcn_mfma_f32_16x16x32_bf16(a0, b0, zacc[nt], 0, 0, 0);
                zacc[nt] = __builtin_amdgcn_mfma_f32_16x16x32_bf16(a1, b1_, zacc[nt], 0, 0, 0);
            }
            #pragma unroll
            for (int nt = 0; nt < 4; ++nt)
                #pragma unroll
                for (int rr = 0; rr < 4; ++rr)
                    Z1s[(nt*16 + fr) * LSTR + (w*16 + fq*4 + rr)] = f2bf(zacc[nt][rr]);
        }
        __syncthreads();
        // ---- LN rows fp32, wave strip; out = xq + gamma*xh + beta ----
        float xqr[16];
        #pragma unroll
        for (int i = 0; i < 16; ++i) {
            int n = c0 + w*16 + i;
            xqr[i] = qkv_b[(size_t)n * 2304 + 0 + lane];
        }
        #pragma unroll
        for (int i = 0; i < 16; ++i) {
            int r = w*16 + i;
            int n = c0 + r;
            float z = bf2f(Z1s[r * LSTR + lane]) + bn1s[lane];
            float mu = wred(z) * 0.015625f;
            float zc = z - mu;
            float var = wred(zc * zc) * 0.015625f;
            float rstd = rsqrtf(var + 1e-6f);
            float xh = zc * rstd;
            inner[(size_t)(b * Ndim + n) * Cdim + h * 64 + lane] =
                f2bf(xqr[i] + gms[lane] * xh + bts[lane]);
        }
        // loop-end barrier folds into next half's post-stage sync via program order:
        // stage(half+1) writes XQs only after this thread's MFMA reads finished;
        // cross-wave safety requires an explicit barrier before restage:
        __syncthreads();
    }
}

extern "C" void kernel_launch(void* const* d_in, const int* in_sizes, int n_in,
                              void* d_out, int out_size, void* d_ws, size_t ws_size,
                              hipStream_t stream) {
    const float* x     = (const float*)d_in[0];
    const float* qkvw  = (const float*)d_in[1];
    const float* qb    = (const float*)d_in[2];
    const float* vb    = (const float*)d_in[3];
    const float* pw    = (const float*)d_in[4];
    const float* pb    = (const float*)d_in[5];
    const float* lrw   = (const float*)d_in[6];
    const float* lrb   = (const float*)d_in[7];
    const float* gamma = (const float*)d_in[8];
    const float* beta  = (const float*)d_in[9];
    const float* W1    = (const float*)d_in[10];
    const float* b1    = (const float*)d_in[11];
    float* out = (float*)d_out;

    // workspace layout
    float* qkv = (float*)d_ws;                                  // 16384*2304 f32
    float* eta = qkv + (size_t)16384 * 2304;                    // 196608 f32
    unsigned short* inner = (unsigned short*)(eta + 196608);    // bf16 16384*768
    unsigned short* xb    = inner + (size_t)16384 * 768;        // bf16 x
    unsigned short* qkvwb = xb + (size_t)16384 * 768;           // bf16 qkv_weight
    unsigned short* pwb   = qkvwb + (size_t)2304 * 768;         // bf16 proj_weight
    float* W1n = (float*)(pwb + (size_t)768 * 768);             // [192,64,64] f32
    float* bn1 = W1n + (size_t)192 * 4096;                      // [192,64] f32

    // 0) casts to bf16
    cast_kernel<<<16384 * 768 / 1024, 256, 0, stream>>>(x, xb);
    cast_kernel<<<2304 * 768 / 1024, 256, 0, stream>>>(qkvw, qkvwb);
    cast_kernel<<<768 * 768 / 1024, 256, 0, stream>>>(pw, pwb);

    // 1) qkv = x @ qkv_weight^T + [q_bias, 0, v_bias]
    gemm_bt_mfma<0><<<dim3(16384 / 128, 2304 / 128), 256, 0, stream>>>(
        (const bf16*)xb, (const bf16*)qkvwb, qb, vb, qkv, 16384, 2304, Cdim);

    // 2) eta
    eta_kernel<<<Bdim * Ndim, 256, 0, stream>>>(x, lrw, lrb, eta);

    // 3) ttt: init -> grad (MFMA, sharded, atomic) -> apply (MFMA, sharded)
    ttt_init<<<Bdim * Hdim, 256, 0, stream>>>(W1, b1, W1n, bn1);
    ttt_grad<<<dim3(Bdim * Hdim, NCH), 256, 0, stream>>>(
        qkv, eta, W1, b1, gamma, beta, W1n, bn1);
    ttt_apply<<<dim3(Bdim * Hdim, NCH), 256, 0, stream>>>(
        qkv, W1n, bn1, gamma, beta, inner);

    // 4) out = inner @ proj_weight^T + proj_bias
    gemm_bt_mfma<1><<<dim3(16384 / 128, 768 / 128), 256, 0, stream>>>(
        (const bf16*)inner, (const bf16*)pwb, pb, nullptr, out, 16384, Cdim, Cdim);
}